// Round 14
// baseline (236.279 us; speedup 1.0000x reference)
//
#include <hip/hip_runtime.h>

typedef unsigned short u16;
typedef __attribute__((ext_vector_type(4))) float f32x4;
typedef __attribute__((ext_vector_type(8))) short short8;
typedef __attribute__((ext_vector_type(4))) short short4v;

#define WIN_SZ 100
#define NWIN 41
#define NBATCH 8
#define SEQ 4096
#define DM 512
#define NHEAD 8
#define KD 64
#define NWINS (NBATCH * NWIN)    // 328
#define MROWS (NWINS * WIN_SZ)   // 32800
#define MBLKS 257                // ceil(32800/128)
#define TOKPB (NWIN * WIN_SZ)    // 4100
#define NQKV 1536
#define CONV_GRID 2048                          // grid-stride conv blocks (G11)
#define GEMM_BLKS (((MBLKS + 7) / 8) * 32)      // 33 panel-groups * 32 = 1056

// ws layout (u16 element offsets)
#define OFF_XBF   0u
#define OFF_OBUF  16793600u                 // + MROWS*DM
#define OFF_WQKVT 33587200u                 // + MROWS*DM
#define OFF_WOT   34373632u                 // + NQKV*DM
#define OFF_ZBLK  34635776u                 // + DM*DM
#define OFF_BIAS  34636032u                 // + 256   (1536 fp32 qkv bias)
#define OFF_BIAS2 34639104u                 // + 3072  (512 fp32 bo)

// 16x16x16 bf16 MFMA (K=16): B-frag k-slice (l>>4)*4+e matches the in-register
// P layout after swapped-QK^T, so PV needs no cross-lane P redistribution.
// NOTE: no __has_builtin guard — it returns false in the HOST pass of hipcc
// (aux-target builtins are callable there but not listed), which broke r6/r7.
#define MFMA16(a, b, c) __builtin_amdgcn_mfma_f32_16x16x16bf16_1k(a, b, c, 0, 0, 0)

// hand-rolled RNE f32->bf16 (kept only for the cold prep-weights path)
__device__ __forceinline__ u16 f2bf(float f) {
  union { float f; unsigned i; } v; v.f = f;
  unsigned r = (v.i + 0x7fffu + ((v.i >> 16) & 1u)) >> 16;
  return (u16)r;
}

// HW paired f32->bf16 (RNE): 1 instruction for 2 values. No builtin on gfx950
// (T12 / m240) — inline asm. Replaced the 4-op bit-twiddle in all hot paths
// (r13: VALUBusy 38->31%, qkvattn 86.5->83.1 us).
__device__ __forceinline__ unsigned cvt_pk_bf16(float a, float b) {
  unsigned r;
  asm("v_cvt_pk_bf16_f32 %0, %1, %2" : "=v"(r) : "v"(a), "v"(b));
  return r;
}

// raw v_exp_f32 (exp2); softmax runs in log2 domain so the per-exp ln2 mul
// disappears (folded into the score scale constant).
__device__ __forceinline__ float exp2_fast(float x) {
  float r;
  asm("v_exp_f32 %0, %1" : "=v"(r) : "v"(x));
  return r;
}

// async global->LDS, 16B per lane; lds base wave-uniform (HW adds lane*16)
__device__ __forceinline__ void gl2lds16(const void* g, void* lds) {
  __builtin_amdgcn_global_load_lds(
      (const __attribute__((address_space(1))) void*)g,
      (__attribute__((address_space(3))) void*)lds, 16, 0, 0);
}

// ---------- merged: x fp32->bf16 window gather (blocks [0,CONV_GRID)) ----------
// ---------- + weight transposes / biases / zblk (blocks [CONV_GRID, +256)) ----
__global__ void prepx_k(const float* __restrict__ x,
                        const float* __restrict__ Wq, const float* __restrict__ Wk,
                        const float* __restrict__ Wv, const float* __restrict__ Wo,
                        const float* __restrict__ bq, const float* __restrict__ bk,
                        const float* __restrict__ bv, const float* __restrict__ bo,
                        u16* __restrict__ ws) {
  __shared__ u16 tile[64][65];
  const int t = threadIdx.x;
  if (blockIdx.x < CONV_GRID) {
    // ---- convx half: grid-stride, 32B in / 16B out per thread-iter ----
    // NT loads: x is read exactly once; keep L2 for xbf (re-read by qkvattn).
    u16* xbf = ws + OFF_XBF;
    const int total = MROWS * 64;               // 32B-group count
    for (int i = blockIdx.x * 256 + t; i < total; i += CONV_GRID * 256) {
      int m = i >> 6;
      int c8 = (i & 63) * 8;
      int b = m / TOKPB, tk = m - b * TOKPB;
      uint4 ov = make_uint4(0u, 0u, 0u, 0u);
      if (tk < SEQ) {
        const float* src = x + (size_t)(b * SEQ + tk) * DM + c8;
        f32x4 v0 = __builtin_nontemporal_load((const f32x4*)src);
        f32x4 v1 = __builtin_nontemporal_load((const f32x4*)(src + 4));
        ov.x = cvt_pk_bf16(v0.x, v0.y);
        ov.y = cvt_pk_bf16(v0.z, v0.w);
        ov.z = cvt_pk_bf16(v1.x, v1.y);
        ov.w = cvt_pk_bf16(v1.z, v1.w);
      }
      *(uint4*)(xbf + (size_t)m * DM + c8) = ov;
    }
    return;
  }
  // ---- prep half: p -> (bx, by, z) of the old dim3(8,8,4) grid ----
  const int p = blockIdx.x - CONV_GRID;
  const int z = p >> 6, by = (p >> 3) & 7, bx = p & 7;
  const float* src = (z == 0) ? Wq : (z == 1) ? Wk : (z == 2) ? Wv : Wo;
  u16* dst = (z < 3) ? (ws + OFF_WQKVT + (unsigned)z * 512u * 512u)
                     : (ws + OFF_WOT);
  const int k0 = by * 64, n0 = bx * 64;
  const int c = t & 63, r4 = t >> 6;
#pragma unroll
  for (int pp = 0; pp < 16; ++pp) {
    int r = pp * 4 + r4;
    tile[r][c] = f2bf(src[(size_t)(k0 + r) * 512 + n0 + c]);
  }
  __syncthreads();
#pragma unroll
  for (int pp = 0; pp < 16; ++pp) {
    int r = pp * 4 + r4;                       // n index within tile
    dst[(size_t)(n0 + r) * 512 + k0 + c] = tile[c][r];
  }
  if (bx == 0 && by == 0) {
    float* biasF = (float*)(ws + OFF_BIAS);
    float* biasO = (float*)(ws + OFF_BIAS2);
    for (int j = t; j < 512; j += 256) {
      if (z == 0) biasF[j] = bq[j];
      else if (z == 1) biasF[512 + j] = bk[j];
      else if (z == 2) biasF[1024 + j] = bv[j];
      else biasO[j] = bo[j];
    }
    if (z == 3 && t < 128) ws[OFF_ZBLK + t] = 0;
  }
}

// -------------- fused QKV projection + attention, one block per (win, head) --------------
#define QKS 72   // Qs/Ks stride
#define PS 136   // Vt stride
// LDS phase-union (u16 elems), total 24832 (49664 B -> 3 blocks/CU):
//   phase1 (staging, dies at post-loop barrier): Xs [0,7168) + Wsl [7168,19456)
//   phase2+: Vt [0,8704) | Qs [8704,16768) | Ks [16768,24832)
//   (no P buffer: softmax->PV stays in registers via swapped QK^T + K=16 PV)
#define SM_ELEMS 24832

__global__ __launch_bounds__(256, 3)
void qkvattn_k(const u16* __restrict__ ws) {
  __shared__ u16 smem[SM_ELEMS];
  u16* Xs  = smem;              // 112 x 64 (column-slot XOR-swizzled per row)
  u16* Wsl = smem + 7168;       // 192 x 64 (column-slot XOR-swizzled per row)
  u16* Vt  = smem;              // 64 x 136
  u16* Qs  = smem + 8704;       // 112 x 72
  u16* Ks  = smem + 16768;      // 112 x 72

  // XCD-locality mapping (T1): all 8 heads of a window share f mod 8 (same
  // XCD L2) and are consecutive in that XCD's stream -> X tile staged 8x
  // while L2-hot. f = (win>>3)*64 + h*8 + (win&7); bijective over 2624.
  const int f = blockIdx.x;
  const int h = (f >> 3) & 7;
  const int win = ((f >> 6) << 3) + (f & 7);

  const int t = threadIdx.x, w = t >> 6, l = t & 63;
  const int q = l >> 4, cl = l & 15;
  // Bank-conflict fix (G4/T2, m173 pattern): pre-swizzle the GLOBAL source
  // column; read-side XOR undoes it. 128B row stride otherwise 16-way conflicts.
  const int lsw = (((t & 7) ^ ((t >> 3) & 7)) * 8);

  // staging source offsets (column pre-swizzled)
  unsigned xoff[4];
#pragma unroll
  for (int i = 0; i < 4; ++i) {
    int m = i * 32 + (t >> 3);
    xoff[i] = (m < WIN_SZ)
                  ? (OFF_XBF + (unsigned)(win * WIN_SZ + m) * DM + lsw)
                  : OFF_ZBLK;
  }
  unsigned woff[6];
#pragma unroll
  for (int i = 0; i < 6; ++i) {
    int g = i * 32 + (t >> 3);
    unsigned nrow = (unsigned)(g >> 6) * 512u + (unsigned)h * 64u + (g & 63);
    woff[i] = OFF_WQKVT + nrow * DM + lsw;
  }

  // ---- phase 1: QKV projection. wave w owns n-tiles {3w,3w+1,3w+2} of 12 ----
  f32x4 acc_p[7][3] = {};
  for (int k0 = 0; k0 < DM; k0 += 64) {
    __syncthreads();
#pragma unroll
    for (int i = 0; i < 4; ++i)
      if (i * 32 + w * 8 < 112)   // wave-uniform
        gl2lds16(ws + xoff[i] + (xoff[i] == OFF_ZBLK ? 0u : (unsigned)k0),
                 &Xs[(i * 32 + w * 8) * 64]);
#pragma unroll
    for (int i = 0; i < 6; ++i)
      gl2lds16(ws + woff[i] + k0, &Wsl[(i * 32 + w * 8) * 64]);
    __syncthreads();
#pragma unroll
    for (int ks = 0; ks < 2; ++ks) {
      const int ko = ks * 32 + q * 8;
      const int koS = ko ^ ((cl & 7) << 3);   // read-side swizzle
      short8 af[7], bf[3];
#pragma unroll
      for (int mt = 0; mt < 7; ++mt)
        af[mt] = *(const short8*)&Xs[(mt * 16 + cl) * 64 + koS];
#pragma unroll
      for (int ntl = 0; ntl < 3; ++ntl)
        bf[ntl] = *(const short8*)&Wsl[((3 * w + ntl) * 16 + cl) * 64 + koS];
      __builtin_amdgcn_s_setprio(1);
#pragma unroll
      for (int mt = 0; mt < 7; ++mt)
#pragma unroll
        for (int ntl = 0; ntl < 3; ++ntl)
          acc_p[mt][ntl] = __builtin_amdgcn_mfma_f32_16x16x32_bf16(
              af[mt], bf[ntl], acc_p[mt][ntl], 0, 0, 0);
      __builtin_amdgcn_s_setprio(0);
    }
  }
  __syncthreads();  // staging reads drained; Vt/Qs/Ks may now overwrite

  // ---- phase 2: accs (+bias) -> Qs / Ks / Vt (paired HW cvt) ----
  {
    const float* biasF = (const float*)(ws + OFF_BIAS);
#pragma unroll
    for (int ntl = 0; ntl < 3; ++ntl) {
      const int nt = 3 * w + ntl;                      // wave-uniform
      const int cw = (nt & 3) * 16 + cl;               // col within Q/K/V
      const float bb = biasF[(nt >> 2) * 512 + h * 64 + cw];
      if (nt < 8) {
        u16* dst = (nt < 4) ? Qs : Ks;
#pragma unroll
        for (int mt = 0; mt < 7; ++mt) {
          const int tok = mt * 16 + q * 4;
          unsigned p01 = cvt_pk_bf16(acc_p[mt][ntl][0] + bb, acc_p[mt][ntl][1] + bb);
          unsigned p23 = cvt_pk_bf16(acc_p[mt][ntl][2] + bb, acc_p[mt][ntl][3] + bb);
          dst[(tok + 0) * QKS + cw] = (u16)p01;
          dst[(tok + 1) * QKS + cw] = (u16)(p01 >> 16);
          dst[(tok + 2) * QKS + cw] = (u16)p23;
          dst[(tok + 3) * QKS + cw] = (u16)(p23 >> 16);
        }
      } else {
        // V: r-index is contiguous in Vt -> 2 cvt_pk feed one b64 write
#pragma unroll
        for (int mt = 0; mt < 7; ++mt) {
          uint2 pv;
          pv.x = cvt_pk_bf16(acc_p[mt][ntl][0] + bb, acc_p[mt][ntl][1] + bb);
          pv.y = cvt_pk_bf16(acc_p[mt][ntl][2] + bb, acc_p[mt][ntl][3] + bb);
          *(uint2*)&Vt[cw * PS + mt * 16 + q * 4] = pv;
        }
      }
    }
    // no Vt pad zeroing needed: PV only reads tokens 0..111 (K=16 tiles),
    // and tokens 100..111 are killed by P=0 from the softmax mask.
  }
  __syncthreads();

  // ---- phase 3: S^T = K Q^T (swapped operands). wave w owns Q-tiles {w, w+4} ----
  // D layout: row = token = nt*16 + q*4 + r (A=K side), col = Q-row = mt*16 + cl.
  const int nmt = (w < 3) ? 2 : 1;
  const int mt0 = w, mt1 = w + 4;

  f32x4 accs[2][7];
#pragma unroll
  for (int im = 0; im < 2; ++im) {
    if (im < nmt) {
      const int mt = (im == 0) ? mt0 : mt1;
      const int ar = (mt * 16 + cl) * QKS + q * 8;
      short8 qa0 = *(const short8*)&Qs[ar];
      short8 qa1 = *(const short8*)&Qs[ar + 32];
      __builtin_amdgcn_s_setprio(1);
#pragma unroll
      for (int nt = 0; nt < 7; ++nt) {
        const int br = (nt * 16 + cl) * QKS + q * 8;
        short8 kb0 = *(const short8*)&Ks[br];
        short8 kb1 = *(const short8*)&Ks[br + 32];
        f32x4 c = {};
        c = __builtin_amdgcn_mfma_f32_16x16x32_bf16(kb0, qa0, c, 0, 0, 0);
        c = __builtin_amdgcn_mfma_f32_16x16x32_bf16(kb1, qa1, c, 0, 0, 0);
        accs[im][nt] = c;
      }
      __builtin_amdgcn_s_setprio(0);
    }
  }

  // softmax in log2 domain (scale' = 1/sqrt(64) * log2(e); exp2 = raw
  // v_exp_f32, no per-exp ln2 mul). In-lane 28 values + 2 shfl over q-group;
  // P packed to bf16 pairs via cvt_pk: pk[im][nt][j] holds tokens
  // nt*16 + 4q + {2j, 2j+1} -- exactly the 16x16x16 B-frag k-slice.
  const float scale2 = 0.18033688011112042f;  // 0.125 * log2(e)
  unsigned pk[2][7][2];
#pragma unroll
  for (int im = 0; im < 2; ++im) {
    if (im < nmt) {
      float mx = -1e30f;
#pragma unroll
      for (int nt = 0; nt < 7; ++nt)
#pragma unroll
        for (int r = 0; r < 4; ++r) {
          float s = accs[im][nt][r] * scale2;
          accs[im][nt][r] = s;
          if ((nt < 6) || (q == 0)) mx = fmaxf(mx, s);   // token<100 valid
        }
      mx = fmaxf(mx, __shfl_xor(mx, 16, 64));
      mx = fmaxf(mx, __shfl_xor(mx, 32, 64));
      float sum = 0.f;
#pragma unroll
      for (int nt = 0; nt < 7; ++nt)
#pragma unroll
        for (int r = 0; r < 4; ++r) {
          bool valid = (nt < 6) || (q == 0);
          float e = valid ? exp2_fast(accs[im][nt][r] - mx) : 0.f;
          accs[im][nt][r] = e;
          sum += e;
        }
      sum += __shfl_xor(sum, 16, 64);
      sum += __shfl_xor(sum, 32, 64);
      float inv = 1.0f / sum;
#pragma unroll
      for (int nt = 0; nt < 7; ++nt) {
        pk[im][nt][0] = cvt_pk_bf16(accs[im][nt][0] * inv, accs[im][nt][1] * inv);
        pk[im][nt][1] = cvt_pk_bf16(accs[im][nt][2] * inv, accs[im][nt][3] * inv);
      }
    }
  }
  // no barrier needed: PV reads only Vt (written before the phase-2 barrier)

  // ---- phase 4: O^T = V^T P^T via K=16 MFMA, P straight from registers ----
  // D: col = Q-row = mt*16+cl, row = kd = vt*16 + q*4 + r.
  f32x4 acco[2][4] = {};
  __builtin_amdgcn_s_setprio(1);
#pragma unroll
  for (int vt = 0; vt < 4; ++vt) {
#pragma unroll
    for (int nt = 0; nt < 7; ++nt) {
      short4v av = *(const short4v*)&Vt[(vt * 16 + cl) * PS + nt * 16 + q * 4];
      union { unsigned u[2]; short4v s; } b0, b1;
      b0.u[0] = pk[0][nt][0]; b0.u[1] = pk[0][nt][1];
      acco[0][vt] = MFMA16(av, b0.s, acco[0][vt]);
      if (nmt == 2) {
        b1.u[0] = pk[1][nt][0]; b1.u[1] = pk[1][nt][1];
        acco[1][vt] = MFMA16(av, b1.s, acco[1][vt]);
      }
    }
  }
  __builtin_amdgcn_s_setprio(0);

  // ---- epilogue: packed 8B stores (regular: 32B chunks need L2 merging —
  // NT here caused 2x HBM write amplification, r11 WRITE_SIZE 33->70MB) ----
  u16* obuf = (u16*)(ws + OFF_OBUF);
  const size_t orow0 = (size_t)win * WIN_SZ;
#pragma unroll
  for (int im = 0; im < 2; ++im) {
    if (im < nmt) {
      const int mt = (im == 0) ? mt0 : mt1;
      const int row = mt * 16 + cl;
      if (row < WIN_SZ) {
#pragma unroll
        for (int vt = 0; vt < 4; ++vt) {
          uint2 ov;
          ov.x = cvt_pk_bf16(acco[im][vt][0], acco[im][vt][1]);
          ov.y = cvt_pk_bf16(acco[im][vt][2], acco[im][vt][3]);
          *(uint2*)&obuf[(orow0 + row) * DM + h * KD + vt * 16 + q * 4] = ov;
        }
      }
    }
  }
}

// ---------------- GEMM: C[M,N] = A[M,512] @ Bt[N,512]^T + bias (fp32 out) ----------------
// Single-barrier double-buffered BK=32 pipeline (r3-verified structure):
// same 32KB LDS footprint as the 2-barrier BK=64 version -> 4 blocks/CU kept,
// same barrier count (16x1 vs 8x2), but next-step loads overlap compute.
__global__ __launch_bounds__(256, 4)
void gemm_k(const u16* __restrict__ ws, unsigned aoff0, unsigned btoff,
            unsigned biasoff, float* __restrict__ Cout, int Ntot) {
  __shared__ u16 smg[2][8192];   // buf b: A [0,4096) 128x32, B [4096,8192) 128x32

  // XCD-locality mapping (T1): the 4 n-blocks sharing an A-panel get ids
  // differing by multiples of 8 (same XCD) and consecutive in that XCD's
  // stream. f = (p>>3)*32 + nb*8 + (p&7); panels padded to 264.
  const int f = blockIdx.x;
  const int nb = (f >> 3) & 3;
  const int p = ((f >> 5) << 3) + (f & 7);
  if (p >= MBLKS) return;

  const int t = threadIdx.x, w = t >> 6, l = t & 63;
  const int m0 = p * 128, n0 = nb * 128;
  const int q = l >> 4, cl = l & 15;

  // staging: 16 gl2lds / K-step; wave w owns ids {w, w+4, w+8, w+12}
  // (id<8: A rows [m0+id*16,+16), else B rows [n0+(id-8)*16,+16); 64B/row)
  unsigned ssrc[4], smask[4], sdst[4];
#pragma unroll
  for (int j = 0; j < 4; ++j) {
    const int id = w + j * 4;
    if (id < 8) {
      const int m = m0 + id * 16 + (l >> 2);
      const bool real = (m < MROWS);
      ssrc[j] = real ? (aoff0 + (unsigned)m * DM + (unsigned)(l & 3) * 8u) : OFF_ZBLK;
      smask[j] = real ? 0xFFFFFFFFu : 0u;
      sdst[j] = (unsigned)id * 512u;
    } else {
      const int n = n0 + (id - 8) * 16 + (l >> 2);
      ssrc[j] = btoff + (unsigned)n * DM + (unsigned)(l & 3) * 8u;
      smask[j] = 0xFFFFFFFFu;
      sdst[j] = 4096u + (unsigned)(id - 8) * 512u;
    }
  }

  f32x4 acc[4][4] = {};
  const int wm = (w & 1) * 64;
  const int wn = (w >> 1) * 64;

  // prologue: stage K-step 0 into buf 0
#pragma unroll
  for (int j = 0; j < 4; ++j) gl2lds16(ws + ssrc[j], &smg[0][sdst[j]]);
  __syncthreads();

  for (int it = 0; it < 16; ++it) {
    const int cur = it & 1;
    if (it < 15) {
      const unsigned k0n = (unsigned)(it + 1) * 32u;
#pragma unroll
      for (int j = 0; j < 4; ++j)
        gl2lds16(ws + ssrc[j] + (k0n & smask[j]), &smg[cur ^ 1][sdst[j]]);
    }
    const u16* Ab = smg[cur];
    const u16* Bb = Ab + 4096;
    const int ko = q * 8;
    short8 av[4], bv_[4];
#pragma unroll
    for (int mi = 0; mi < 4; ++mi)
      av[mi] = *(const short8*)&Ab[(wm + mi * 16 + cl) * 32 + ko];
#pragma unroll
    for (int ni = 0; ni < 4; ++ni)
      bv_[ni] = *(const short8*)&Bb[(wn + ni * 16 + cl) * 32 + ko];
    __builtin_amdgcn_s_setprio(1);
#pragma unroll
    for (int mi = 0; mi < 4; ++mi)
#pragma unroll
      for (int ni = 0; ni < 4; ++ni)
        acc[mi][ni] = __builtin_amdgcn_mfma_f32_16x16x32_bf16(
            av[mi], bv_[ni], acc[mi][ni], 0, 0, 0);
    __builtin_amdgcn_s_setprio(0);
    __syncthreads();   // drains this iter's prefetch (vmcnt0) + buf reads (lgkm)
  }

  const float* biasF = (const float*)(ws + biasoff);
#pragma unroll
  for (int mi = 0; mi < 4; ++mi) {
#pragma unroll
    for (int ni = 0; ni < 4; ++ni) {
      int col = n0 + wn + ni * 16 + cl;
      float bb = biasF[col];
#pragma unroll
      for (int r = 0; r < 4; ++r) {
        int row = m0 + wm + mi * 16 + q * 4 + r;
        if (row < MROWS)
          __builtin_nontemporal_store(acc[mi][ni][r] + bb,
                                      &Cout[(size_t)row * Ntot + col]);
      }
    }
  }
}

extern "C" void kernel_launch(void* const* d_in, const int* in_sizes, int n_in,
                              void* d_out, int out_size, void* d_ws, size_t ws_size,
                              hipStream_t stream) {
  const float* x  = (const float*)d_in[0];
  const float* Wq = (const float*)d_in[1];
  const float* bq = (const float*)d_in[2];
  const float* Wk = (const float*)d_in[3];
  const float* bk = (const float*)d_in[4];
  const float* Wv = (const float*)d_in[5];
  const float* bv = (const float*)d_in[6];
  const float* Wo = (const float*)d_in[7];
  const float* bo = (const float*)d_in[8];

  u16* ws = (u16*)d_ws;

  prepx_k<<<dim3(CONV_GRID + 256), dim3(256), 0, stream>>>(
      x, Wq, Wk, Wv, Wo, bq, bk, bv, bo, ws);
  qkvattn_k<<<dim3(NWINS * NHEAD), dim3(256), 0, stream>>>(ws);
  gemm_k<<<dim3(GEMM_BLKS), dim3(256), 0, stream>>>(
      ws, OFF_OBUF, OFF_WOT, OFF_BIAS2, (float*)d_out, DM);
}